// Round 3
// baseline (237.812 us; speedup 1.0000x reference)
//
#include <hip/hip_runtime.h>
#include <math.h>

#define NBLK 4096
#define NTHR 256

// ws layout: [0, NBLK*8) double partials; [NBLK*8, +4) counter; [NBLK*8+16, ...) float4 pts
// pts[p] = (z0x, z0y, v0x, v0y)

typedef float v2 __attribute__((ext_vector_type(2)));

__device__ __forceinline__ v2 vfma2(v2 a, v2 b, v2 c) {
    v2 r; r.x = fmaf(a.x, b.x, c.x); r.y = fmaf(a.y, b.y, c.y); return r;
}

__global__ void pack_kernel(const float* __restrict__ z0,
                            const float* __restrict__ v0,
                            float4* __restrict__ pts,
                            unsigned int* __restrict__ counter, int n_pts) {
    int p = blockIdx.x * blockDim.x + threadIdx.x;
    if (p < n_pts)
        pts[p] = make_float4(z0[2 * p], z0[2 * p + 1], v0[2 * p], v0[2 * p + 1]);
    if (p == 0) *counter = 0u;
}

// signed erf tail: returns sgn(x) * P(t(|x|)) * exp2(eL - x^2*log2e)
// (A&S 7.1.26: erf(x) = sgn(x)*(1 - P*exp(-x^2)), |err| <= 1.5e-7)
__device__ __forceinline__ float erf_term(float x, float eL) {
    const float L2E = 1.4426950408889634f;
    float ax = fabsf(x);
    float tt = __builtin_amdgcn_rcpf(fmaf(0.3275911f, ax, 1.0f));
    float P = tt * fmaf(tt, fmaf(tt, fmaf(tt, fmaf(tt, 1.061405429f, -1.453152027f),
                        1.421413741f), -0.284496736f), 0.254829592f);
    float arg = fmaf(x * L2E, -x, eL);
    float PE = P * __builtin_amdgcn_exp2f(arg);
    return copysignf(PE, x);
}

__device__ __forceinline__ void decode_k(long long k, int n, int& oi, int& oj) {
    double nn = 2.0 * n - 1.0;
    int i = (int)((nn - sqrt(fmax(nn * nn - 8.0 * (double)k, 0.0))) * 0.5);
    i = max(0, min(i, n - 2));
    while ((long long)(i + 1) * (2LL * n - i - 2) / 2 <= k) ++i;
    while ((long long)i * (2LL * n - i - 1) / 2 > k) --i;
    oi = i;
    oj = i + 1 + (int)(k - (long long)i * (2LL * n - i - 1) / 2);
}

__device__ __forceinline__ void advance(int& i, int& j, int n, int step) {
    j += step;
    while (j >= n) {
        if (i >= n - 2) { i = n - 2; j = n - 1; break; }
        int over = j - n;
        ++i;
        j = i + 1 + over;
    }
}

__global__ __launch_bounds__(NTHR) void cvm_main_kernel(
    const int2* __restrict__ idx, const float* __restrict__ t,
    const float4* __restrict__ pts,
    const float* __restrict__ t0p, const float* __restrict__ tnp,
    const float* __restrict__ betap,
    int n_events, int n_pts,
    double* __restrict__ partials, unsigned int* __restrict__ counter,
    float* __restrict__ out) {

    const float b  = betap[0];
    const float t0 = t0p[0];
    const float tn = tnp[0];
    const int tid = blockIdx.x * NTHR + threadIdx.x;
    const int nthreads = gridDim.x * NTHR;

    v2 acc = {0.f, 0.f};

    // ---- Event part: grid-stride, coalesced idx/t, float4 gathers (L1/L2-hot)
    for (int e = tid; e < n_events; e += nthreads) {
        int2 ij  = idx[e];
        float te = t[e];
        float4 pi = pts[ij.x];
        float4 pj = pts[ij.y];
        float dx = (pi.x - pj.x) + (pi.z - pj.z) * te;
        float dy = (pi.y - pj.y) + (pi.w - pj.w) * te;
        acc.x = fmaf(dx, dx, fmaf(dy, dy, acc.x));
    }

    // ---- Pair part: equal flat-index chunks per wave, TWO pairs per lane per
    // iter (A at k, B at k+64; stride 128) -> packed f32 + 2 independent chains.
    const long long P = (long long)n_pts * (n_pts - 1) / 2;
    const int n_waves = nthreads >> 6;
    const int wave = tid >> 6;
    const int lane = threadIdx.x & 63;
    const long long per = (P + n_waves - 1) / n_waves;
    const long long k0 = (long long)wave * per;
    const long long kend = (k0 + per < P) ? (k0 + per) : P;

    const float SPI2 = 0.88622692545275801365f;  // sqrt(pi)/2
    const float L2E  = 1.4426950408889634f;

    long long kA = k0 + lane;
    if (kA < kend) {
        int iA, jA, iB, jB;
        decode_k(kA, n_pts, iA, jA);
        long long kB = kA + 64;
        decode_k((kB < P) ? kB : (P - 1), n_pts, iB, jB);

        #pragma unroll 2
        for (; kA < kend; kA += 128) {
            bool validB = (kA + 64) < kend;
            float4 PiA = pts[iA], PjA = pts[jA];
            float4 PiB = pts[iB], PjB = pts[jB];

            v2 dzx = {PiA.x - PjA.x, PiB.x - PjB.x};
            v2 dzy = {PiA.y - PjA.y, PiB.y - PjB.y};
            v2 dvx = {PiA.z - PjA.z, PiB.z - PjB.z};
            v2 dvy = {PiA.w - PjA.w, PiB.w - PjB.w};

            v2 a2 = vfma2(dzx, dzx, dzy * dzy);
            v2 b2 = vfma2(dvx, dvx, dvy * dvy);
            v2 ab = vfma2(dzx, dvx, dzy * dvy);
            v2 r;  r.x = __builtin_amdgcn_rsqf(b2.x); r.y = __builtin_amdgcn_rsqf(b2.y);
            v2 mu = ab * (r * r);
            v2 bma2 = {b - a2.x, b - a2.y};
            v2 e0 = vfma2(ab, mu, bma2);
            v2 eL = e0 * L2E;
            v2 bn = b2 * r;
            v2 tnmu = {tn + mu.x, tn + mu.y};
            v2 t0mu = {t0 + mu.x, t0 + mu.y};
            v2 x1 = bn * tnmu;
            v2 x0 = bn * t0mu;

            v2 pe1; pe1.x = erf_term(x1.x, eL.x); pe1.y = erf_term(x1.y, eL.y);
            v2 pe0; pe0.x = erf_term(x0.x, eL.x); pe0.y = erf_term(x0.y, eL.y);

            // jump term: 2*exp(e0) iff x0 < 0 <= x1
            v2 E0; E0.x = __builtin_amdgcn_exp2f(eL.x); E0.y = __builtin_amdgcn_exp2f(eL.y);
            float jx = (x0.x < 0.f && x1.x >= 0.f) ? 2.f * E0.x : 0.f;
            float jy = (x0.y < 0.f && x1.y >= 0.f) ? 2.f * E0.y : 0.f;

            v2 sum = {jx + pe0.x - pe1.x, jy + pe0.y - pe1.y};
            if (!validB) sum.y = 0.f;
            v2 w = r * SPI2;
            acc = vfma2(w, sum, acc);

            advance(iA, jA, n_pts, 128);
            advance(iB, jB, n_pts, 128);
        }
    }

    // ---- Block reduce (double), store partial, last block finishes
    double v = (double)acc.x + (double)acc.y;
    #pragma unroll
    for (int off = 32; off > 0; off >>= 1) v += __shfl_down(v, off, 64);
    __shared__ double wsum[4];
    __shared__ bool is_last;
    if ((threadIdx.x & 63) == 0) wsum[threadIdx.x >> 6] = v;
    __syncthreads();
    if (threadIdx.x == 0) {
        partials[blockIdx.x] = wsum[0] + wsum[1] + wsum[2] + wsum[3];
        __threadfence();
        unsigned int old = atomicAdd(counter, 1u);
        is_last = (old == (unsigned int)(gridDim.x - 1));
    }
    __syncthreads();

    if (is_last) {
        __threadfence();
        double s = 0.0;
        for (int i = threadIdx.x; i < NBLK; i += NTHR) s += partials[i];
        #pragma unroll
        for (int off = 32; off > 0; off >>= 1) s += __shfl_down(s, off, 64);
        if ((threadIdx.x & 63) == 0) wsum[threadIdx.x >> 6] = s;
        __syncthreads();
        if (threadIdx.x == 0)
            out[0] = (float)((double)n_events * (double)betap[0] -
                             (wsum[0] + wsum[1] + wsum[2] + wsum[3]));
    }
}

extern "C" void kernel_launch(void* const* d_in, const int* in_sizes, int n_in,
                              void* d_out, int out_size, void* d_ws, size_t ws_size,
                              hipStream_t stream) {
    const int2*  idx  = (const int2*)d_in[0];
    const float* t    = (const float*)d_in[1];
    const float* t0   = (const float*)d_in[2];
    const float* tn   = (const float*)d_in[3];
    const float* z0   = (const float*)d_in[4];
    const float* v0   = (const float*)d_in[5];
    const float* beta = (const float*)d_in[6];
    const int n_events = in_sizes[1];
    const int n_pts    = in_sizes[4] / 2;

    double* partials = (double*)d_ws;
    unsigned int* counter = (unsigned int*)((char*)d_ws + NBLK * sizeof(double));
    float4* pts = (float4*)((char*)d_ws + NBLK * sizeof(double) + 16);

    pack_kernel<<<(n_pts + NTHR - 1) / NTHR, NTHR, 0, stream>>>(z0, v0, pts,
                                                                counter, n_pts);
    cvm_main_kernel<<<NBLK, NTHR, 0, stream>>>(idx, t, pts, t0, tn, beta,
                                               n_events, n_pts, partials,
                                               counter, (float*)d_out);
}

// Round 4
// 185.931 us; speedup vs baseline: 1.2790x; 1.2790x over previous
//
#include <hip/hip_runtime.h>
#include <math.h>

#define NTHR 256
#define ROWS 64     // rows per block tile (one per lane)
#define COLW 128    // cols per block tile (32 per wave)
#define MAXBLK 8192

// ws layout: [0, MAXBLK*8) double partials; [MAXBLK*8, +4) counter;
//            [MAXBLK*8+16, ...) float4 pts: (z0x, z0y, v0x, v0y)

__global__ void pack_kernel(const float* __restrict__ z0,
                            const float* __restrict__ v0,
                            float4* __restrict__ pts,
                            unsigned int* __restrict__ counter, int n_pts) {
    int p = blockIdx.x * blockDim.x + threadIdx.x;
    if (p < n_pts)
        pts[p] = make_float4(z0[2 * p], z0[2 * p + 1], v0[2 * p], v0[2 * p + 1]);
    if (p == 0) *counter = 0u;
}

// signed erf tail: sgn(x) * P(t(|x|)) * exp2(eL - x^2*log2e)
// (A&S 7.1.26: erf(x) = sgn(x)*(1 - P*exp(-x^2)), |err| <= 1.5e-7)
__device__ __forceinline__ float erf_term(float x, float eL) {
    const float L2E = 1.4426950408889634f;
    float ax = fabsf(x);
    float tt = __builtin_amdgcn_rcpf(fmaf(0.3275911f, ax, 1.0f));
    float P = tt * fmaf(tt, fmaf(tt, fmaf(tt, fmaf(tt, 1.061405429f, -1.453152027f),
                        1.421413741f), -0.284496736f), 0.254829592f);
    float arg = fmaf(x * L2E, -x, eL);
    float PE = P * __builtin_amdgcn_exp2f(arg);
    return copysignf(PE, x);
}

__global__ __launch_bounds__(NTHR) void cvm_main_kernel(
    const int2* __restrict__ idx, const float* __restrict__ t,
    const float4* __restrict__ pts,
    const float* __restrict__ t0p, const float* __restrict__ tnp,
    const float* __restrict__ betap,
    int n_events, int n_pts,
    double* __restrict__ partials, unsigned int* __restrict__ counter,
    float* __restrict__ out) {

    const float b  = betap[0];
    const float t0 = t0p[0];
    const float tn = tnp[0];
    const float SPI2 = 0.88622692545275801365f;  // sqrt(pi)/2
    const float L2E  = 1.4426950408889634f;

    const int bid = blockIdx.y * gridDim.x + blockIdx.x;
    const int nblocks = gridDim.x * gridDim.y;
    const int c0 = blockIdx.x * COLW;
    const int r0 = blockIdx.y * ROWS;

    // ---- Stage column tile into LDS (hot-loop reads are wave-uniform -> broadcast)
    __shared__ float4 tile[COLW];
    if (threadIdx.x < COLW) {
        int jg = c0 + threadIdx.x;
        tile[threadIdx.x] = pts[min(jg, n_pts - 1)];
    }

    float accf = 0.0f;  // Sum(d_event) + Sum(integral) contributions; final = N*b - total

    // ---- Event part: grid-stride, coalesced idx/t, float4 gathers (L2-hot 80KB)
    for (int e = bid * NTHR + threadIdx.x; e < n_events; e += nblocks * NTHR) {
        int2 ij  = idx[e];
        float te = t[e];
        float4 pi = pts[ij.x];
        float4 pj = pts[ij.y];
        float dx = (pi.x - pj.x) + (pi.z - pj.z) * te;
        float dy = (pi.y - pj.y) + (pi.w - pj.w) * te;
        accf = fmaf(dx, dx, fmaf(dy, dy, accf));
    }

    // ---- Pair part: lane owns row i = r0+lane; wave w sweeps 32 cols from LDS.
    const bool tile_valid = (c0 + COLW - 1) > r0;   // block-uniform
    if (tile_valid) {
        __syncthreads();
        const int lane = threadIdx.x & 63;
        const int w = threadIdx.x >> 6;
        const int i = r0 + lane;
        const float4 Pi = pts[min(i, n_pts - 1)];   // coalesced, register-cached
        const int jbase = c0 + w * 32;
        const int jcount = min(32, n_pts - jbase);  // wave-uniform bound
        const bool diag = (c0 < r0 + ROWS);         // only diagonal tiles need j>i mask

        #pragma unroll 8
        for (int jj = 0; jj < jcount; ++jj) {
            int j = jbase + jj;
            float4 Pj = tile[j - c0];               // broadcast LDS read
            float dzx = Pi.x - Pj.x, dzy = Pi.y - Pj.y;
            float dvx = Pi.z - Pj.z, dvy = Pi.w - Pj.w;
            float a2 = fmaf(dzx, dzx, dzy * dzy);
            float b2 = fmaf(dvx, dvx, dvy * dvy);
            float ab = fmaf(dzx, dvx, dzy * dvy);
            float r  = __builtin_amdgcn_rsqf(b2);   // 1/bnorm
            float mu = ab * (r * r);
            float e0 = fmaf(ab, mu, b - a2);        // <= b by Cauchy-Schwarz
            float eL = e0 * L2E;
            float bn = b2 * r;
            float x1 = bn * (tn + mu);
            float x0 = bn * (t0 + mu);
            float pe1 = erf_term(x1, eL);
            float pe0 = erf_term(x0, eL);
            float E0 = __builtin_amdgcn_exp2f(eL);
            float jump = (x0 < 0.f && x1 >= 0.f) ? 2.f * E0 : 0.f;
            float val = (SPI2 * r) * (jump + pe0 - pe1);
            if (!diag || j > i)                      // predicated accumulate
                accf += val;
        }
    }

    // ---- Block reduce (double), store partial, last block finishes
    double v = (double)accf;
    #pragma unroll
    for (int off = 32; off > 0; off >>= 1) v += __shfl_down(v, off, 64);
    __shared__ double wsum[4];
    __shared__ bool is_last;
    if ((threadIdx.x & 63) == 0) wsum[threadIdx.x >> 6] = v;
    __syncthreads();
    if (threadIdx.x == 0) {
        partials[bid] = wsum[0] + wsum[1] + wsum[2] + wsum[3];
        __threadfence();
        unsigned int old = atomicAdd(counter, 1u);
        is_last = (old == (unsigned int)(nblocks - 1));
    }
    __syncthreads();

    if (is_last) {
        __threadfence();
        double s = 0.0;
        for (int i = threadIdx.x; i < nblocks; i += NTHR) s += partials[i];
        #pragma unroll
        for (int off = 32; off > 0; off >>= 1) s += __shfl_down(s, off, 64);
        if ((threadIdx.x & 63) == 0) wsum[threadIdx.x >> 6] = s;
        __syncthreads();
        if (threadIdx.x == 0)
            out[0] = (float)((double)n_events * (double)betap[0] -
                             (wsum[0] + wsum[1] + wsum[2] + wsum[3]));
    }
}

extern "C" void kernel_launch(void* const* d_in, const int* in_sizes, int n_in,
                              void* d_out, int out_size, void* d_ws, size_t ws_size,
                              hipStream_t stream) {
    const int2*  idx  = (const int2*)d_in[0];
    const float* t    = (const float*)d_in[1];
    const float* t0   = (const float*)d_in[2];
    const float* tn   = (const float*)d_in[3];
    const float* z0   = (const float*)d_in[4];
    const float* v0   = (const float*)d_in[5];
    const float* beta = (const float*)d_in[6];
    const int n_events = in_sizes[1];
    const int n_pts    = in_sizes[4] / 2;

    double* partials = (double*)d_ws;
    unsigned int* counter = (unsigned int*)((char*)d_ws + MAXBLK * sizeof(double));
    float4* pts = (float4*)((char*)d_ws + MAXBLK * sizeof(double) + 16);

    const int n_col_tiles = (n_pts + COLW - 1) / COLW;            // 40 for n=5000
    const int n_row_tiles = (n_pts - 1 + ROWS - 1) / ROWS;        // 79 for n=5000
    dim3 grid(n_col_tiles, n_row_tiles);                          // 3160 blocks

    pack_kernel<<<(n_pts + NTHR - 1) / NTHR, NTHR, 0, stream>>>(z0, v0, pts,
                                                                counter, n_pts);
    cvm_main_kernel<<<grid, NTHR, 0, stream>>>(idx, t, pts, t0, tn, beta,
                                               n_events, n_pts, partials,
                                               counter, (float*)d_out);
}

// Round 5
// 101.534 us; speedup vs baseline: 2.3422x; 1.8312x over previous
//
#include <hip/hip_runtime.h>
#include <math.h>

#define NTHR 256
#define MAXBLK 4096

// ws layout: [0, MAXBLK*8) double partials; [MAXBLK*8, ...) float4 pts
// pts[p] = (z0x, z0y, v0x, v0y)

__global__ void pack_kernel(const float* __restrict__ z0,
                            const float* __restrict__ v0,
                            float4* __restrict__ pts, int n_pts) {
    int p = blockIdx.x * blockDim.x + threadIdx.x;
    if (p < n_pts)
        pts[p] = make_float4(z0[2 * p], z0[2 * p + 1], v0[2 * p], v0[2 * p + 1]);
}

// signed erf tail: sgn(x) * P(t(|x|)) * exp2(eL - x^2*log2e)
// (A&S 7.1.26: erf(x) = sgn(x)*(1 - P*exp(-x^2)), |err| <= 1.5e-7)
// HW-verified in R3/R4 (absmax 0.0 vs np reference).
__device__ __forceinline__ float erf_term(float x, float eL) {
    const float L2E = 1.4426950408889634f;
    float ax = fabsf(x);
    float tt = __builtin_amdgcn_rcpf(fmaf(0.3275911f, ax, 1.0f));
    float P = tt * fmaf(tt, fmaf(tt, fmaf(tt, fmaf(tt, 1.061405429f, -1.453152027f),
                        1.421413741f), -0.284496736f), 0.254829592f);
    float arg = fmaf(x * L2E, -x, eL);
    return copysignf(P * __builtin_amdgcn_exp2f(arg), x);
}

// integral term for one (i,j) pair; pref*exp folded into erf tails.
__device__ __forceinline__ float pair_val(float4 Pi, float4 Pj,
                                          float b, float t0, float tn) {
    const float SPI2 = 0.88622692545275801365f;  // sqrt(pi)/2
    const float L2E  = 1.4426950408889634f;
    float dzx = Pi.x - Pj.x, dzy = Pi.y - Pj.y;
    float dvx = Pi.z - Pj.z, dvy = Pi.w - Pj.w;
    float a2 = fmaf(dzx, dzx, dzy * dzy);
    float b2 = fmaf(dvx, dvx, dvy * dvy);
    float ab = fmaf(dzx, dvx, dzy * dvy);
    float r  = __builtin_amdgcn_rsqf(b2);      // 1/bnorm
    float mu = ab * (r * r);
    float e0 = fmaf(ab, mu, b - a2);           // <= b by Cauchy-Schwarz
    float eL = e0 * L2E;
    float bn = b2 * r;
    float x1 = bn * (tn + mu);
    float x0 = bn * (t0 + mu);
    float pe1 = erf_term(x1, eL);
    float pe0 = erf_term(x0, eL);
    float jump = (x0 < 0.f && x1 >= 0.f)
                     ? 2.f * __builtin_amdgcn_exp2f(eL) : 0.f;
    return (SPI2 * r) * (jump + pe0 - pe1);
}

__global__ __launch_bounds__(NTHR) void cvm_main_kernel(
    const int2* __restrict__ idx, const float* __restrict__ t,
    const float4* __restrict__ pts,
    const float* __restrict__ t0p, const float* __restrict__ tnp,
    const float* __restrict__ betap,
    int n_events, int n_pts, double* __restrict__ partials) {

    const float b  = betap[0];
    const float t0 = t0p[0];
    const float tn = tnp[0];
    const int nblocks = gridDim.x;

    float accf = 0.0f;  // Sum(d_event) + Sum(integral); final = N*b - total

    // ---- Event part: grid-stride, coalesced idx/t stream, float4 gathers
    // (80KB table, L1/L2-hot; ~31K wave-gathers total -> a few us)
    for (int e = blockIdx.x * NTHR + threadIdx.x; e < n_events;
         e += nblocks * NTHR) {
        int2 ij  = idx[e];
        float te = t[e];
        float4 pi = pts[ij.x];
        float4 pj = pts[ij.y];
        float dx = (pi.x - pj.x) + (pi.z - pj.z) * te;
        float dy = (pi.y - pj.y) + (pi.w - pj.w) * te;
        accf = fmaf(dx, dx, fmaf(dy, dy, accf));
    }

    // ---- Pair part: block b owns rows {b, n_rows-1-b} -> exactly n_pts pairs
    // per block (perfect balance). Lanes take consecutive j -> coalesced
    // pts[j]; Pi is a single broadcast load, register-cached.
    const int n_rows = n_pts - 1;  // rows 0..n_pts-2 have pairs
    const int r1 = blockIdx.x;
    if (r1 < n_rows) {
        const int r2 = n_rows - 1 - r1;
        float4 Pi = pts[r1];
        for (int j = r1 + 1 + threadIdx.x; j < n_pts; j += NTHR)
            accf += pair_val(Pi, pts[j], b, t0, tn);
        if (r2 > r1) {
            float4 Pi2 = pts[r2];
            for (int j = r2 + 1 + threadIdx.x; j < n_pts; j += NTHR)
                accf += pair_val(Pi2, pts[j], b, t0, tn);
        }
    }

    // ---- Block reduce (double), plain store — no atomics, no fences
    double v = (double)accf;
    #pragma unroll
    for (int off = 32; off > 0; off >>= 1) v += __shfl_down(v, off, 64);
    __shared__ double wsum[4];
    if ((threadIdx.x & 63) == 0) wsum[threadIdx.x >> 6] = v;
    __syncthreads();
    if (threadIdx.x == 0)
        partials[blockIdx.x] = wsum[0] + wsum[1] + wsum[2] + wsum[3];
}

__global__ void finish_kernel(const double* __restrict__ partials, int nblk,
                              const float* __restrict__ betap,
                              float* __restrict__ out, int n_events) {
    double v = 0.0;
    for (int i = threadIdx.x; i < nblk; i += NTHR) v += partials[i];
    #pragma unroll
    for (int off = 32; off > 0; off >>= 1) v += __shfl_down(v, off, 64);
    __shared__ double wsum[4];
    if ((threadIdx.x & 63) == 0) wsum[threadIdx.x >> 6] = v;
    __syncthreads();
    if (threadIdx.x == 0)
        out[0] = (float)((double)n_events * (double)betap[0] -
                         (wsum[0] + wsum[1] + wsum[2] + wsum[3]));
}

extern "C" void kernel_launch(void* const* d_in, const int* in_sizes, int n_in,
                              void* d_out, int out_size, void* d_ws, size_t ws_size,
                              hipStream_t stream) {
    const int2*  idx  = (const int2*)d_in[0];
    const float* t    = (const float*)d_in[1];
    const float* t0   = (const float*)d_in[2];
    const float* tn   = (const float*)d_in[3];
    const float* z0   = (const float*)d_in[4];
    const float* v0   = (const float*)d_in[5];
    const float* beta = (const float*)d_in[6];
    const int n_events = in_sizes[1];
    const int n_pts    = in_sizes[4] / 2;

    double* partials = (double*)d_ws;
    float4* pts = (float4*)((char*)d_ws + MAXBLK * sizeof(double));

    const int n_rows = n_pts - 1;
    int nblk = (n_rows + 1) / 2;          // 2500 for n_pts=5000
    if (nblk < 1) nblk = 1;
    if (nblk > MAXBLK) nblk = MAXBLK;     // safety (n_pts fixed at 5000)

    pack_kernel<<<(n_pts + NTHR - 1) / NTHR, NTHR, 0, stream>>>(z0, v0, pts, n_pts);
    cvm_main_kernel<<<nblk, NTHR, 0, stream>>>(idx, t, pts, t0, tn, beta,
                                               n_events, n_pts, partials);
    finish_kernel<<<1, NTHR, 0, stream>>>(partials, nblk, beta,
                                          (float*)d_out, n_events);
}